// Round 11
// baseline (376.638 us; speedup 1.0000x reference)
//
#include <hip/hip_runtime.h>

#define H_ 1024
#define W_ 1024
#define B_ 4
#define CIN 16
#define COUT 16
#define TH 4
#define TW 256
#define NT 8          // tiles per block strip (strip = 32 rows)
#define SROWS 6       // TH+2 staged rows
#define COLS_U 290    // swz(257)=289 -> 290 16B-units per row-plane

#define LRELU 0.2f
#define GAIN_ 1.4142135623730951f
#define EPS_ 1e-8f

// LDS-only barrier (no vmcnt drain): prefetch loads/stores stay in flight.
#define BAR_LGKM()                                                      \
    do {                                                                \
        __builtin_amdgcn_sched_barrier(0);                              \
        asm volatile("s_waitcnt lgkmcnt(0)\n\ts_barrier" ::: "memory"); \
        __builtin_amdgcn_sched_barrier(0);                              \
    } while (0)

typedef __attribute__((ext_vector_type(8))) short bf16x8;
typedef __attribute__((ext_vector_type(16))) float f32x16;

static __device__ __forceinline__ unsigned short f32_to_bf16(float f) {
    unsigned int u = __float_as_uint(f);
    unsigned int r = u + 0x7FFF + ((u >> 16) & 1);   // RNE
    return (unsigned short)(r >> 16);
}

static __device__ __forceinline__ float f4c(const float4& v, int px) {
    return px == 0 ? v.x : px == 1 ? v.y : px == 2 ? v.z : v.w;
}

static __device__ __forceinline__ int swz(int c) { return c + (c >> 3); }

// ---------------- setup 1: s[b,i] = w @ (fcw.T * 512^-0.5) + bias; copy w to out ----
__global__ __launch_bounds__(256) void k_setup1(
    const float* __restrict__ w, const float* __restrict__ fcw,
    const float* __restrict__ fcb, float* __restrict__ s_out,
    float* __restrict__ w_copy_out)
{
    __shared__ float part[256];
    const int tid = threadIdx.x;
    const int bi = tid >> 2;   // 0..63 -> (b,i)
    const int q  = tid & 3;
    const int b = bi >> 4, i = bi & 15;
    const float* wr = w + b * 512 + q * 128;
    const float* fr = fcw + i * 512 + q * 128;
    float acc = 0.f;
    #pragma unroll 8
    for (int k = 0; k < 128; ++k) acc += wr[k] * fr[k];
    part[tid] = acc;
    __syncthreads();
    if (tid < 64) {
        float v = part[tid*4] + part[tid*4+1] + part[tid*4+2] + part[tid*4+3];
        s_out[tid] = v * 0.04419417382415922f /* 512^-0.5 */ + fcb[tid & 15];
    }
    for (int e = tid; e < B_ * 512; e += 256) w_copy_out[e] = w[e];
}

// ---------------- setup 2: d[b,o], W_eff -> 32x32x16 A-fragments (P/Q packed) -------
// frag f = 0..5: f<3 -> P(C=f): m-half R=0 -> tap C, R=1 -> tap 3+C
//               f>=3 -> Q(C=f-3): R=0 -> tap 6+C, R=1 -> zero
__global__ __launch_bounds__(256) void k_setup2(
    const float* __restrict__ s_in, const float* __restrict__ convw,
    unsigned short* __restrict__ afrag)
{
    const int b = blockIdx.x;
    const int tid = threadIdx.x;
    __shared__ float s_sh[16];
    __shared__ float d_sh[16];
    __shared__ float wc_sh[COUT * CIN * 9];
    __shared__ float part[256];

    if (tid < 16) s_sh[tid] = s_in[b * 16 + tid];
    for (int e = tid; e < COUT * CIN * 9; e += 256)
        wc_sh[e] = convw[e] * (1.0f / 12.0f);   // (16*9)^-0.5
    __syncthreads();

    const int o = tid >> 4, i = tid & 15;
    const float si = s_sh[i];
    float acc = 0.f;
    #pragma unroll
    for (int tap = 0; tap < 9; ++tap) {
        float v = wc_sh[(o * 16 + i) * 9 + tap] * si;
        acc += v * v;
    }
    part[tid] = acc;
    __syncthreads();
    if (tid < 16) {
        float sum = EPS_;
        #pragma unroll
        for (int j = 0; j < 16; ++j) sum += part[tid * 16 + j];
        d_sh[tid] = rsqrtf(sum);
    }
    __syncthreads();

    for (int e = tid; e < 6 * 64 * 8; e += 256) {
        const int f    = e >> 9;         // 0..5
        const int lane = (e >> 3) & 63;
        const int j    = e & 7;
        const int C    = (f < 3) ? f : (f - 3);
        const bool isQ = (f >= 3);
        const int oo = lane & 15;
        const int R  = (lane >> 4) & 1;
        const int ii = 8 * (lane >> 5) + j;
        int tap;
        if (!isQ) tap = 3 * R + C;                 // rows 0,1
        else      tap = (R == 0) ? (6 + C) : -1;   // row 2 / zero pad
        float v = 0.f;
        if (tap >= 0) v = wc_sh[(oo * 16 + ii) * 9 + tap] * s_sh[ii] * d_sh[oo];
        afrag[(size_t)b * (6 * 64 * 8) + e] = f32_to_bf16(v);
    }
}

// ---------------- main conv: wide-tile wave-specialized implicit GEMM ---------------
// 512 thr: waves 0..3 compute (64 px each), waves 4..7 stage (3 units/thread).
// One global_load_dwordx4 instruction = 1KB contiguous of one channel row.
// nt stores; per (o,row) the block writes 1KB contiguous. P/Q 32x32 chains as r10.
__global__ __launch_bounds__(512, 4) void k_conv(
    const float* __restrict__ x, const float* __restrict__ noise,
    const float* __restrict__ conv_bias, const float* __restrict__ sn_ptr,
    const unsigned short* __restrict__ afrag, float* __restrict__ y)
{
    __shared__ unsigned short tile[2][SROWS][COLS_U][8]; // 55680 B

    const int tid = threadIdx.x;
    const int bt = blockIdx.z;
    const int h0s = blockIdx.y * (TH * NT);
    const int w0 = blockIdx.x * TW;
    const float sn = sn_ptr[0];
    const float* xb = x + (size_t)bt * CIN * H_ * W_;
    float* yb = y + (size_t)bt * COUT * H_ * W_;
    const float* nb = noise + (size_t)bt * H_ * W_;

    const int lane = tid & 63;
    const int wid  = tid >> 6;           // 0..7
    const bool isStage = (wid >= 4);
    const int s = tid - 256;             // staging thread index (valid if isStage)

    // staging: 768 interior units (row 0..5, hh, cg 0..63), 3 per staging thread;
    // 24 edge units on staging threads 0..23.
    const bool hasE = isStage && (s < 24);
    const int rowE = s >> 2, sideE = (s >> 1) & 1, hhE = s & 1;

    float4 vS[3][8];
    float  ev[8];

    auto stage_load = [&](int t) {
        if (!isStage) return;
        const int gh0 = h0s + TH * t - 1;
        #pragma unroll
        for (int k = 0; k < 3; ++k) {
            const int u = s + 256 * k;
            const int row = u >> 7, hh = (u >> 6) & 1, cg = u & 63;
            const int gh = gh0 + row;
            const bool ok = (gh >= 0) && (gh < H_);
            const float* base = xb + ((size_t)(8 * hh) * H_ + gh) * W_ + (w0 + 4 * cg);
            #pragma unroll
            for (int c = 0; c < 8; ++c) {
                vS[k][c] = make_float4(0.f, 0.f, 0.f, 0.f);
                if (ok) vS[k][c] = *reinterpret_cast<const float4*>(base + (size_t)c * H_ * W_);
            }
        }
        if (hasE) {
            const int gh = gh0 + rowE;
            const int gw = w0 - 1 + sideE * 257;
            const bool ok = (gh >= 0) && (gh < H_) && (gw >= 0) && (gw < W_);
            #pragma unroll
            for (int c = 0; c < 8; ++c)
                ev[c] = ok ? xb[((size_t)(8 * hhE + c) * H_ + gh) * W_ + gw] : 0.f;
        }
    };

    auto stage_write = [&]() {
        if (!isStage) return;
        #pragma unroll
        for (int k = 0; k < 3; ++k) {
            const int u = s + 256 * k;
            const int row = u >> 7, hh = (u >> 6) & 1, cg = u & 63;
            #pragma unroll
            for (int px = 0; px < 4; ++px) {
                bf16x8 pk;
                #pragma unroll
                for (int c = 0; c < 8; ++c) pk[c] = (short)f32_to_bf16(f4c(vS[k][c], px));
                *reinterpret_cast<bf16x8*>(&tile[hh][row][swz(1 + 4 * cg + px)][0]) = pk;
            }
        }
        if (hasE) {
            bf16x8 pk;
            #pragma unroll
            for (int c = 0; c < 8; ++c) pk[c] = (short)f32_to_bf16(ev[c]);
            *reinterpret_cast<bf16x8*>(&tile[hhE][rowE][sideE ? swz(257) : 0][0]) = pk;
        }
    };

    // ---- compute-wave constants ----
    const int posBase = wid * 64;        // 64 px per compute wave
    const int chalfB  = lane >> 5;

    bf16x8 aP[3], aQ[3];
    {
        const bf16x8* ap = reinterpret_cast<const bf16x8*>(afrag + (size_t)bt * 6 * 64 * 8);
        #pragma unroll
        for (int C = 0; C < 3; ++C) {
            aP[C] = ap[C * 64 + lane];
            aQ[C] = ap[(3 + C) * 64 + lane];
        }
    }
    int   o_j[8];
    float bias_j[8];
    #pragma unroll
    for (int j = 0; j < 8; ++j) {
        o_j[j] = (j & 3) + 8 * (j >> 2) + 4 * chalfB;
        bias_j[j] = conv_bias[o_j[j]];
    }

    float nv[8];                         // [pos 2][row 4]
    auto noise_prefetch = [&](int t) {
        if (isStage) return;
        const int ghB = h0s + TH * t;
        #pragma unroll
        for (int ip = 0; ip < 2; ++ip)
            #pragma unroll
            for (int r = 0; r < 4; ++r)
                nv[ip * 4 + r] =
                    nb[(size_t)(ghB + r) * W_ + w0 + posBase + ip * 32 + (lane & 31)];
    };

// One sweep row: born chain (slot K%3), finish chain C_{K-2}, emit row K-2.
// out[r] = C_r.h0 + C_{r+1}.h1 (h1 complete after P-birth; Q's R=1 is zero).
#define KROW(K, BORN, PREV, FIN, CB, NVO)                                            \
    {                                                                                \
        const unsigned short* rbase = &tile[chalfB][(K)][0][0];                      \
        bf16x8 bv0 = *reinterpret_cast<const bf16x8*>(&rbase[swz((CB) + 0) * 8]);    \
        bf16x8 bv1 = *reinterpret_cast<const bf16x8*>(&rbase[swz((CB) + 1) * 8]);    \
        bf16x8 bv2 = *reinterpret_cast<const bf16x8*>(&rbase[swz((CB) + 2) * 8]);    \
        if ((K) <= 4) {                                                              \
            _Pragma("unroll")                                                        \
            for (int i_ = 0; i_ < 16; ++i_) BORN[i_] = 0.f;                          \
            BORN = __builtin_amdgcn_mfma_f32_32x32x16_bf16(aP[0], bv0, BORN, 0, 0, 0); \
            BORN = __builtin_amdgcn_mfma_f32_32x32x16_bf16(aP[1], bv1, BORN, 0, 0, 0); \
            BORN = __builtin_amdgcn_mfma_f32_32x32x16_bf16(aP[2], bv2, BORN, 0, 0, 0); \
        }                                                                            \
        if ((K) >= 2) {                                                              \
            FIN = __builtin_amdgcn_mfma_f32_32x32x16_bf16(aQ[0], bv0, FIN, 0, 0, 0); \
            FIN = __builtin_amdgcn_mfma_f32_32x32x16_bf16(aQ[1], bv1, FIN, 0, 0, 0); \
            FIN = __builtin_amdgcn_mfma_f32_32x32x16_bf16(aQ[2], bv2, FIN, 0, 0, 0); \
            const int r_ = (K) - 2;                                                  \
            const int gh_ = ghBase + r_;                                             \
            const float noi_ = nv[(NVO) + r_] * sn;                                  \
            _Pragma("unroll")                                                        \
            for (int j_ = 0; j_ < 8; ++j_) {                                         \
                float v_ = FIN[j_] + PREV[8 + j_] + bias_j[j_] + noi_;               \
                v_ = (v_ >= 0.f) ? v_ : (LRELU * v_);                                \
                __builtin_nontemporal_store(v_ * GAIN_,                              \
                    &yb[((size_t)o_j[j_] * H_ + gh_) * W_ + w0 + (CB)]);             \
            }                                                                        \
        }                                                                            \
    }

    auto compute = [&](int t) {
        if (isStage) return;
        const int ghBase = h0s + TH * t;
        __builtin_amdgcn_s_setprio(1);
        {
            const int CB = posBase + (lane & 31);
            f32x16 c0, c1, c2;
            KROW(0, c0, c2, c1, CB, 0);
            KROW(1, c1, c0, c2, CB, 0);
            KROW(2, c2, c1, c0, CB, 0);
            KROW(3, c0, c2, c1, CB, 0);
            KROW(4, c1, c0, c2, CB, 0);
            KROW(5, c2, c1, c0, CB, 0);
        }
        {
            const int CB = posBase + 32 + (lane & 31);
            f32x16 c0, c1, c2;
            KROW(0, c0, c2, c1, CB, 4);
            KROW(1, c1, c0, c2, CB, 4);
            KROW(2, c2, c1, c0, CB, 4);
            KROW(3, c0, c2, c1, CB, 4);
            KROW(4, c1, c0, c2, CB, 4);
            KROW(5, c2, c1, c0, CB, 4);
        }
        __builtin_amdgcn_s_setprio(0);
    };

    // ---- persistent pipeline (prefetch t+1 across compute t) ----
    stage_load(0);
    for (int t = 0; t < NT; ++t) {
        if (t > 0) BAR_LGKM();           // compute waves done reading tile t-1
        noise_prefetch(t);                // compute waves: noise t in flight
        stage_write();                    // staging waves: vmcnt-waits load(t)
        BAR_LGKM();                       // tile t visible
        if (t + 1 < NT) stage_load(t + 1);
        compute(t);
    }
}

extern "C" void kernel_launch(void* const* d_in, const int* in_sizes, int n_in,
                              void* d_out, int out_size, void* d_ws, size_t ws_size,
                              hipStream_t stream)
{
    const float* w     = (const float*)d_in[0];
    const float* x     = (const float*)d_in[1];
    const float* noise = (const float*)d_in[2];
    const float* fcw   = (const float*)d_in[3];
    const float* fcb   = (const float*)d_in[4];
    const float* convw = (const float*)d_in[5];
    const float* convb = (const float*)d_in[6];
    const float* sn    = (const float*)d_in[7];

    float* out = (float*)d_out;
    float* ws_s = (float*)d_ws;                                        // 64 f32
    unsigned short* ws_afrag = (unsigned short*)((char*)d_ws + 256);   // 4*3072 u16

    k_setup1<<<1, 256, 0, stream>>>(w, fcw, fcb, ws_s, out);
    k_setup2<<<B_, 256, 0, stream>>>(ws_s, convw, ws_afrag);
    dim3 grid(W_ / TW, H_ / (TH * NT), B_);
    k_conv<<<grid, 512, 0, stream>>>(x, noise, convb, sn, ws_afrag, out + 2048);
}